// Round 3
// baseline (456.018 us; speedup 1.0000x reference)
//
#include <hip/hip_runtime.h>
#include <hip/hip_cooperative_groups.h>
namespace cg = cooperative_groups;

#define TOK   65536
#define HID   768
#define NSEQ  128
#define FFD   3072
#define CHUNK 64
#define CPB   4          // chunks per block (256 blocks * 4 * 64 = 65536 tokens)
#define GRID  256
#define KCH   160
#define KS1   5          // 5*160 covers 768 (last split = 128)
#define KS2   20         // 20*160 covers 3072 (last split = 32)

__device__ __forceinline__ void add4(float4& a, const float4 b) {
  a.x += b.x; a.y += b.y; a.z += b.z; a.w += b.w;
}

// One 128s x 64f tile of C = A[128 x Kt] * B[N x Kt]^T over k-range
// [k0, min(k0+KCH,Kt)). A may be NSUM partial slabs spaced pstride apart
// (folded during staging). Thread tile 8s x 4f, 256 threads.
template <int NSUM>
__device__ void gemm_tile(const float* __restrict__ A, const float* __restrict__ B,
                          float* __restrict__ C, int N, int Kt, int f0, int k0,
                          int pstride, int tid) {
  __shared__ float As[16][132];   // [k][s]; pad -> worst 2-way bank alias (free)
  __shared__ float Bs[16][68];    // [k][f]

  const int kend = (k0 + KCH) < Kt ? (k0 + KCH) : Kt;
  const int fx = (tid & 15) * 4;
  const int sy = (tid >> 4) * 8;

  float acc[8][4];
  #pragma unroll
  for (int i = 0; i < 8; ++i)
    #pragma unroll
    for (int j = 0; j < 4; ++j) acc[i][j] = 0.f;

  for (int kc = k0; kc < kend; kc += 16) {
    #pragma unroll
    for (int r = 0; r < 2; ++r) {            // stage A: 128x16 via float4-of-k
      const int l = tid + 256 * r;
      const int s = l >> 2, k4 = (l & 3) * 4;
      const float* ap = A + (size_t)s * Kt + kc + k4;
      float4 v = *(const float4*)ap;
      #pragma unroll
      for (int p = 1; p < NSUM; ++p) add4(v, *(const float4*)(ap + (size_t)p * pstride));
      As[k4 + 0][s] = v.x; As[k4 + 1][s] = v.y;
      As[k4 + 2][s] = v.z; As[k4 + 3][s] = v.w;
    }
    {                                        // stage B: 64x16 via float4-of-k
      const int f = tid >> 2, k4 = (tid & 3) * 4;
      const float4 v = *(const float4*)(B + (size_t)(f0 + f) * Kt + kc + k4);
      Bs[k4 + 0][f] = v.x; Bs[k4 + 1][f] = v.y;
      Bs[k4 + 2][f] = v.z; Bs[k4 + 3][f] = v.w;
    }
    __syncthreads();
    #pragma unroll
    for (int kk = 0; kk < 16; ++kk) {
      const float4 aA = *(const float4*)&As[kk][sy];
      const float4 aB = *(const float4*)&As[kk][sy + 4];
      const float4 bb = *(const float4*)&Bs[kk][fx];
      acc[0][0] += aA.x*bb.x; acc[0][1] += aA.x*bb.y; acc[0][2] += aA.x*bb.z; acc[0][3] += aA.x*bb.w;
      acc[1][0] += aA.y*bb.x; acc[1][1] += aA.y*bb.y; acc[1][2] += aA.y*bb.z; acc[1][3] += aA.y*bb.w;
      acc[2][0] += aA.z*bb.x; acc[2][1] += aA.z*bb.y; acc[2][2] += aA.z*bb.z; acc[2][3] += aA.z*bb.w;
      acc[3][0] += aA.w*bb.x; acc[3][1] += aA.w*bb.y; acc[3][2] += aA.w*bb.z; acc[3][3] += aA.w*bb.w;
      acc[4][0] += aB.x*bb.x; acc[4][1] += aB.x*bb.y; acc[4][2] += aB.x*bb.z; acc[4][3] += aB.x*bb.w;
      acc[5][0] += aB.y*bb.x; acc[5][1] += aB.y*bb.y; acc[5][2] += aB.y*bb.z; acc[5][3] += aB.y*bb.w;
      acc[6][0] += aB.z*bb.x; acc[6][1] += aB.z*bb.y; acc[6][2] += aB.z*bb.z; acc[6][3] += aB.z*bb.w;
      acc[7][0] += aB.w*bb.x; acc[7][1] += aB.w*bb.y; acc[7][2] += aB.w*bb.z; acc[7][3] += aB.w*bb.w;
    }
    __syncthreads();
  }
  #pragma unroll
  for (int i = 0; i < 8; ++i)
    *(float4*)(C + (size_t)(sy + i) * N + f0 + fx) =
        make_float4(acc[i][0], acc[i][1], acc[i][2], acc[i][3]);
}

__global__ __launch_bounds__(256) void fused_kernel(
    const float* __restrict__ x, const int* __restrict__ lens,
    const float* __restrict__ W1, const float* __restrict__ W2,
    float* __restrict__ out, float* __restrict__ pooled,
    float* __restrict__ h1p, float* __restrict__ outp) {
  cg::grid_group grid = cg::this_grid();
  const int tid = threadIdx.x;
  const int b = blockIdx.x;
  __shared__ int sc[NSEQ];      // inclusive scan of lens (persists across phases)
  __shared__ float wsum[4];

  // ---- phase 0: zero pooled (atomic target) + per-block scan of lens ----
  if (b < 96) ((float4*)pooled)[b * 256 + tid] = make_float4(0.f, 0.f, 0.f, 0.f);
  if (tid < NSEQ) sc[tid] = lens[tid];
  __syncthreads();
  for (int off = 1; off < NSEQ; off <<= 1) {   // Hillis-Steele
    int v = 0;
    if (tid < NSEQ && tid >= off) v = sc[tid - off];
    __syncthreads();
    if (tid < NSEQ) sc[tid] += v;
    __syncthreads();
  }
  grid.sync();

  // ---- phase 1: segment mean-pool; 192 lanes = float4 columns ----
  if (tid < 192) {
    const int col = tid;
    const float4* xv = (const float4*)x + col;
    for (int c = 0; c < CPB; ++c) {
      const int t0 = (b * CPB + c) * CHUNK;
      const int t1 = t0 + CHUNK;
      int lo = 0, hi = NSEQ - 1;               // first seg with incl > t0
      while (lo < hi) { int mid = (lo + hi) >> 1; if (sc[mid] <= t0) lo = mid + 1; else hi = mid; }
      int seg = lo;
      int segend = sc[seg];
      int L = seg ? segend - sc[seg - 1] : segend;
      int t = t0;
      while (t < t1) {
        const int run_end = segend < t1 ? segend : t1;
        const int n = run_end - t;
        const float4* p = xv + (size_t)t * (HID / 4);
        float4 a0 = make_float4(0.f,0.f,0.f,0.f), a1 = a0, a2 = a0, a3 = a0,
               a4 = a0, a5 = a0, a6 = a0, a7 = a0;
        int i = 0;
        for (; i + 8 <= n; i += 8) {           // 8 outstanding loads
          add4(a0, p[(size_t)(i+0) * 192]); add4(a1, p[(size_t)(i+1) * 192]);
          add4(a2, p[(size_t)(i+2) * 192]); add4(a3, p[(size_t)(i+3) * 192]);
          add4(a4, p[(size_t)(i+4) * 192]); add4(a5, p[(size_t)(i+5) * 192]);
          add4(a6, p[(size_t)(i+6) * 192]); add4(a7, p[(size_t)(i+7) * 192]);
        }
        for (; i < n; ++i) add4(a0, p[(size_t)i * 192]);
        add4(a0, a1); add4(a2, a3); add4(a4, a5); add4(a6, a7);
        add4(a0, a2); add4(a4, a6); add4(a0, a4);

        const float inv = 1.0f / (float)L;
        float* dst = pooled + (size_t)seg * HID + col * 4;
        atomicAdd(dst + 0, a0.x * inv);
        atomicAdd(dst + 1, a0.y * inv);
        atomicAdd(dst + 2, a0.z * inv);
        atomicAdd(dst + 3, a0.w * inv);

        t = run_end;
        if (run_end == segend) {
          ++seg;
          if (seg < NSEQ) { const int pe = segend; segend = sc[seg]; L = segend - pe; }
        }
      }
    }
  }
  grid.sync();

  // ---- phase 2: gemm1 — h1p[5][128,3072] partials of pooled @ W1^T ----
  if (b < 48 * KS1)
    gemm_tile<1>(pooled, W1, h1p + (size_t)(b / 48) * NSEQ * FFD,
                 FFD, HID, (b % 48) * 64, (b / 48) * KCH, 0, tid);
  grid.sync();

  // ---- phase 3: gemm2 — outp[20][128,768] partials of (sum h1p) @ W2^T ----
  if (b < 12 * KS2)
    gemm_tile<KS1>(h1p, W2, outp + (size_t)(b / 12) * NSEQ * HID,
                   HID, FFD, (b % 12) * 64, (b / 12) * KCH, NSEQ * FFD, tid);
  grid.sync();

  // ---- phase 4: sum gemm2 partials + L2 normalize ----
  if (b < NSEQ) {
    const int s = b;
    float v[3];
    #pragma unroll
    for (int j = 0; j < 3; ++j) {
      const int cidx = tid + 256 * j;
      float a = 0.f;
      for (int p = 0; p < KS2; ++p) a += outp[((size_t)p * NSEQ + s) * HID + cidx];
      v[j] = a;
    }
    float ss = v[0]*v[0] + v[1]*v[1] + v[2]*v[2];
    #pragma unroll
    for (int off = 32; off > 0; off >>= 1) ss += __shfl_down(ss, off, 64);
    if ((tid & 63) == 0) wsum[tid >> 6] = ss;
    __syncthreads();
    const float tot = wsum[0] + wsum[1] + wsum[2] + wsum[3];
    const float scale = 1.0f / fmaxf(sqrtf(tot), 1e-12f);
    #pragma unroll
    for (int j = 0; j < 3; ++j) out[(size_t)s * HID + tid + 256 * j] = v[j] * scale;
  }
}

extern "C" void kernel_launch(void* const* d_in, const int* in_sizes, int n_in,
                              void* d_out, int out_size, void* d_ws, size_t ws_size,
                              hipStream_t stream) {
  const float* x    = (const float*)d_in[0];  // [65536, 768]
  const int*   lens = (const int*)d_in[1];    // [128]
  const float* W1   = (const float*)d_in[2];  // [3072, 768]
  const float* W2   = (const float*)d_in[3];  // [768, 3072]
  float* out = (float*)d_out;                 // [128, 768]

  float* pooled = (float*)d_ws;                       // 128*768
  float* h1p    = pooled + NSEQ * HID;                // 5*128*3072
  float* outp   = h1p + (size_t)KS1 * NSEQ * FFD;     // 20*128*768

  void* args[] = {(void*)&x, (void*)&lens, (void*)&W1, (void*)&W2,
                  (void*)&out, (void*)&pooled, (void*)&h1p, (void*)&outp};
  hipLaunchCooperativeKernel((void*)fused_kernel, dim3(GRID), dim3(256),
                             args, 0, stream);
}

// Round 4
// 338.695 us; speedup vs baseline: 1.3464x; 1.3464x over previous
//
#include <hip/hip_runtime.h>

#define TOK   65536
#define HID   768
#define NSEQ  128
#define FFD   3072
#define PCH   32               // tokens per pool chunk (min seg len >= 34 -> <=1 boundary/chunk)
#define NPCH  (TOK / PCH)      // 2048 blocks
#define KS1   8
#define KCH1  96               // 8 * 96  = 768
#define KS2   24
#define KCH2  128              // 24 * 128 = 3072

__device__ __forceinline__ void add4(float4& a, const float4 b) {
  a.x += b.x; a.y += b.y; a.z += b.z; a.w += b.w;
}

// Segment mean-pool, built for HBM saturation: 2048 blocks x 192 threads
// (24 waves/CU), each block = 32 consecutive tokens, thread = one float4 col.
// Fast path (no boundary): 32 fully-unrolled independent loads -> deep MLP.
__global__ __launch_bounds__(192, 6) void pool_kernel(
    const float* __restrict__ x, const int* __restrict__ lens,
    float* __restrict__ pooled) {
  __shared__ int sc[NSEQ];
  const int tid = threadIdx.x;
  if (tid < NSEQ) sc[tid] = lens[tid];
  __syncthreads();
  for (int off = 1; off < NSEQ; off <<= 1) {   // Hillis-Steele inclusive scan
    int v = 0;
    if (tid < NSEQ && tid >= off) v = sc[tid - off];
    __syncthreads();
    if (tid < NSEQ) sc[tid] += v;
    __syncthreads();
  }
  const int t0 = blockIdx.x * PCH;
  int lo = 0, hi = NSEQ - 1;                   // first seg with incl > t0
  while (lo < hi) { int mid = (lo + hi) >> 1; if (sc[mid] <= t0) lo = mid + 1; else hi = mid; }
  const int seg = lo;
  const int segend = sc[seg];
  const int segstart = seg ? sc[seg - 1] : 0;
  const float4* p = (const float4*)x + (size_t)t0 * (HID / 4) + tid;

  if (segend >= t0 + PCH) {
    // fast path: whole chunk in one segment; 32 independent loads
    float4 a0 = make_float4(0.f,0.f,0.f,0.f), a1 = a0, a2 = a0, a3 = a0;
    #pragma unroll
    for (int i = 0; i < PCH; i += 4) {
      add4(a0, p[(size_t)(i+0) * (HID/4)]);
      add4(a1, p[(size_t)(i+1) * (HID/4)]);
      add4(a2, p[(size_t)(i+2) * (HID/4)]);
      add4(a3, p[(size_t)(i+3) * (HID/4)]);
    }
    add4(a0, a1); add4(a2, a3); add4(a0, a2);
    const float inv = 1.0f / (float)(segend - segstart);
    float* dst = pooled + (size_t)seg * HID + tid * 4;
    atomicAdd(dst + 0, a0.x * inv);
    atomicAdd(dst + 1, a0.y * inv);
    atomicAdd(dst + 2, a0.z * inv);
    atomicAdd(dst + 3, a0.w * inv);
  } else {
    // boundary chunk (rare, ~6%): two runs
    const int n0 = segend - t0;                // 1..31
    float4 a0 = make_float4(0.f,0.f,0.f,0.f), a1 = a0;
    for (int i = 0; i < n0; ++i)  add4(a0, p[(size_t)i * (HID/4)]);
    for (int i = n0; i < PCH; ++i) add4(a1, p[(size_t)i * (HID/4)]);
    const float inv0 = 1.0f / (float)(segend - segstart);
    const float inv1 = 1.0f / (float)(sc[seg + 1] - segend);
    float* d0 = pooled + (size_t)seg * HID + tid * 4;
    atomicAdd(d0 + 0, a0.x * inv0);
    atomicAdd(d0 + 1, a0.y * inv0);
    atomicAdd(d0 + 2, a0.z * inv0);
    atomicAdd(d0 + 3, a0.w * inv0);
    float* d1 = pooled + (size_t)(seg + 1) * HID + tid * 4;
    atomicAdd(d1 + 0, a1.x * inv1);
    atomicAdd(d1 + 1, a1.y * inv1);
    atomicAdd(d1 + 2, a1.z * inv1);
    atomicAdd(d1 + 3, a1.w * inv1);
  }
}

// Cp[by][128 x N] = A[128 x Kt] * B[N x Kt]^T over this ksplit's k-range.
// Tile 128s x 32f, 256 threads, thread tile 4s x 4f (low VGPR -> high occ).
__global__ __launch_bounds__(256) void gemm_nt(
    const float* __restrict__ A, const float* __restrict__ B,
    float* __restrict__ Cp, int N, int Kt, int kch) {
  __shared__ float As[16][132];   // [k][s], 2-way max bank alias (free)
  __shared__ float Bs[16][36];    // [k][f]

  const int tid = threadIdx.x;
  const int f0 = blockIdx.x * 32;
  const int k0 = blockIdx.y * kch;
  float* C = Cp + (size_t)blockIdx.y * NSEQ * N;
  const int fx = (tid & 7) * 4;
  const int sy = (tid >> 3) * 4;

  float acc[4][4];
  #pragma unroll
  for (int i = 0; i < 4; ++i)
    #pragma unroll
    for (int j = 0; j < 4; ++j) acc[i][j] = 0.f;

  for (int kc = k0; kc < k0 + kch; kc += 16) {
    #pragma unroll
    for (int r = 0; r < 2; ++r) {              // stage A: 128x16 via float4-of-k
      const int l = tid + 256 * r;
      const int s = l >> 2, k4 = (l & 3) * 4;
      const float4 v = *(const float4*)(A + (size_t)s * Kt + kc + k4);
      As[k4 + 0][s] = v.x; As[k4 + 1][s] = v.y;
      As[k4 + 2][s] = v.z; As[k4 + 3][s] = v.w;
    }
    if (tid < 128) {                           // stage B: 32x16 via float4-of-k
      const int f = tid >> 2, k4 = (tid & 3) * 4;
      const float4 v = *(const float4*)(B + (size_t)(f0 + f) * Kt + kc + k4);
      Bs[k4 + 0][f] = v.x; Bs[k4 + 1][f] = v.y;
      Bs[k4 + 2][f] = v.z; Bs[k4 + 3][f] = v.w;
    }
    __syncthreads();
    #pragma unroll
    for (int kk = 0; kk < 16; ++kk) {
      const float4 aa = *(const float4*)&As[kk][sy];
      const float4 bb = *(const float4*)&Bs[kk][fx];
      acc[0][0] += aa.x*bb.x; acc[0][1] += aa.x*bb.y; acc[0][2] += aa.x*bb.z; acc[0][3] += aa.x*bb.w;
      acc[1][0] += aa.y*bb.x; acc[1][1] += aa.y*bb.y; acc[1][2] += aa.y*bb.z; acc[1][3] += aa.y*bb.w;
      acc[2][0] += aa.z*bb.x; acc[2][1] += aa.z*bb.y; acc[2][2] += aa.z*bb.z; acc[2][3] += aa.z*bb.w;
      acc[3][0] += aa.w*bb.x; acc[3][1] += aa.w*bb.y; acc[3][2] += aa.w*bb.z; acc[3][3] += aa.w*bb.w;
    }
    __syncthreads();
  }
  #pragma unroll
  for (int i = 0; i < 4; ++i)
    *(float4*)(C + (size_t)(sy + i) * N + f0 + fx) =
        make_float4(acc[i][0], acc[i][1], acc[i][2], acc[i][3]);
}

// h1 = sum of the KS1 gemm1 partial slabs. One float4 per thread.
__global__ __launch_bounds__(256) void reduce_h1(
    const float* __restrict__ h1p, float* __restrict__ h1) {
  const size_t i = (size_t)blockIdx.x * 256 + threadIdx.x;  // < 98304 float4s
  const float4* src = (const float4*)h1p;
  float4 a = src[i];
  #pragma unroll
  for (int p = 1; p < KS1; ++p) add4(a, src[i + (size_t)p * (NSEQ * FFD / 4)]);
  ((float4*)h1)[i] = a;
}

// Fold the KS2 gemm2 partials + L2 normalize each row.
__global__ __launch_bounds__(256) void norm_kernel(
    const float* __restrict__ outp, float* __restrict__ out) {
  const int s = blockIdx.x;
  const int tid = threadIdx.x;
  float v[3];
  #pragma unroll
  for (int j = 0; j < 3; ++j) {
    const int c = tid + 256 * j;
    float a = 0.f;
    for (int p = 0; p < KS2; ++p) a += outp[((size_t)p * NSEQ + s) * HID + c];
    v[j] = a;
  }
  float ss = v[0]*v[0] + v[1]*v[1] + v[2]*v[2];
  #pragma unroll
  for (int off = 32; off > 0; off >>= 1) ss += __shfl_down(ss, off, 64);
  __shared__ float wsum[4];
  if ((tid & 63) == 0) wsum[tid >> 6] = ss;
  __syncthreads();
  const float tot = wsum[0] + wsum[1] + wsum[2] + wsum[3];
  const float scale = 1.0f / fmaxf(sqrtf(tot), 1e-12f);
  #pragma unroll
  for (int j = 0; j < 3; ++j) out[(size_t)s * HID + tid + 256 * j] = v[j] * scale;
}

extern "C" void kernel_launch(void* const* d_in, const int* in_sizes, int n_in,
                              void* d_out, int out_size, void* d_ws, size_t ws_size,
                              hipStream_t stream) {
  const float* x    = (const float*)d_in[0];  // [65536, 768]
  const int*   lens = (const int*)d_in[1];    // [128]
  const float* W1   = (const float*)d_in[2];  // [3072, 768]
  const float* W2   = (const float*)d_in[3];  // [768, 3072]
  float* out = (float*)d_out;                 // [128, 768]

  float* pooled = (float*)d_ws;                       // 128*768
  float* h1p    = pooled + NSEQ * HID;                // 8 * 128*3072
  float* h1     = h1p + (size_t)KS1 * NSEQ * FFD;     // 128*3072
  float* outp   = h1 + NSEQ * FFD;                    // 24 * 128*768

  hipMemsetAsync(pooled, 0, (size_t)NSEQ * HID * sizeof(float), stream);

  pool_kernel<<<NPCH, 192, 0, stream>>>(x, lens, pooled);
  gemm_nt<<<dim3(FFD / 32, KS1), 256, 0, stream>>>(pooled, W1, h1p, FFD, HID, KCH1);
  reduce_h1<<<NSEQ * FFD / 4 / 256, 256, 0, stream>>>(h1p, h1);
  gemm_nt<<<dim3(HID / 32, KS2), 256, 0, stream>>>(h1, W2, outp, HID, FFD, KCH2);
  norm_kernel<<<NSEQ, 256, 0, stream>>>(outp, out);
}